// Round 1
// baseline (128.025 us; speedup 1.0000x reference)
//
#include <hip/hip_runtime.h>
#include <hip/hip_cooperative_groups.h>
#include <math.h>

#define N 4096

namespace cg = cooperative_groups;

// ---------------------------------------------------------------------------
// Fused kernel (cooperative, 256 blocks x 256 threads, 1 block/CU).
// Phase 1: byte-identical R3 rank-by-counting (8 lanes/element, 2 rows).
// grid.sync()
// Phase 2: block 0 only (256 threads): prefix scan of z, chord prune, tiny
//          serial Graham hull per row, epilogue (Pearson + BCE in double).
// Saves one kernel launch + full-device drain vs the 2-kernel version.
// ---------------------------------------------------------------------------
__global__ __launch_bounds__(256) void fused_kernel(
        const float* __restrict__ yh, const float* __restrict__ yv,
        float* __restrict__ sA, float* __restrict__ sB,
        int* __restrict__ posA, int* __restrict__ posB,
        float* __restrict__ out) {
    // ---------------- Phase 1: rank (identical math to prior K1) ----------
    {
        int g = blockIdx.x * 256 + threadIdx.x;   // 0..65535
        int elem = g >> 3;                        // 0..8191
        int k = g & 7;                            // stripe
        int row = elem >> 12;
        int i = elem & (N - 1);
        const float* X = row ? yv : yh;
        float x = X[i];
        const float4* X4 = (const float4*)X;
        int cnt = 0;
        int m0 = k * 128;                         // 128 float4 = 512 elems/stripe
#pragma unroll 4
        for (int m = m0; m < m0 + 128; ++m) {
            float4 f = X4[m];
            int j = 4 * m;
            cnt += (int)(f.x > x) | ((int)(f.x == x) & (int)((j + 0) < i));
            cnt += (int)(f.y > x) | ((int)(f.y == x) & (int)((j + 1) < i));
            cnt += (int)(f.z > x) | ((int)(f.z == x) & (int)((j + 2) < i));
            cnt += (int)(f.w > x) | ((int)(f.w == x) & (int)((j + 3) < i));
        }
        cnt += __shfl_xor(cnt, 1, 8);
        cnt += __shfl_xor(cnt, 2, 8);
        cnt += __shfl_xor(cnt, 4, 8);
        if (k == 0) {
            if (row) { posB[i] = cnt; sB[cnt] = x; }
            else     { posA[i] = cnt; sA[cnt] = x; }
        }
    }

    __threadfence();                // release our writes to device scope
    cg::this_grid().sync();         // all 256 blocks arrive

    if (blockIdx.x != 0) return;
    __threadfence();                // acquire: invalidate stale L1/L2 lines

    // ---------------- Phase 2: finalize on 256 threads ---------------------
    __shared__ double wT[4];                    // per-wave scan totals
    __shared__ unsigned short survX[2][512];
    __shared__ double survY[2][512];
    __shared__ unsigned short gX[2][516];
    __shared__ double gY[2][516];
    __shared__ double gSlope[2][516];
    __shared__ int survCnt[2];
    __shared__ int Hsh[2];
    __shared__ double wred[4][6];

    const int tid  = threadIdx.x;               // 0..255
    const int lane = tid & 63;
    const int wave = tid >> 6;                  // 0..3
    const int r    = tid >> 7;                  // 0: row A, 1: row B
    const int t    = tid & 127;                 // thread within row
    const int q0   = t * 32;                    // first element of this thread

    // epilogue loads issued early to hide latency under scan/hull
    int4 pa4[4], pb4[4]; float4 xh4[4], yt4[4];
#pragma unroll
    for (int u = 0; u < 4; ++u) {
        pa4[u] = ((const int4*)posA)[4 * tid + u];
        pb4[u] = ((const int4*)posB)[4 * tid + u];
        xh4[u] = ((const float4*)yh)[4 * tid + u];
        yt4[u] = ((const float4*)yv)[4 * tid + u];
    }

    const float* S = r ? sB : sA;
    float4 sv4[8];
#pragma unroll
    for (int u = 0; u < 8; ++u) sv4[u] = ((const float4*)S)[8 * t + u];

    // ---- per-thread total of z = s_q - (N - q) over 32 elements ----
    double acc = 0.0;
#pragma unroll
    for (int u = 0; u < 8; ++u) {
        int q = q0 + 4 * u;
        acc += (double)sv4[u].x - (double)(N - (q + 0));
        acc += (double)sv4[u].y - (double)(N - (q + 1));
        acc += (double)sv4[u].z - (double)(N - (q + 2));
        acc += (double)sv4[u].w - (double)(N - (q + 3));
    }
    double tot = acc, incl = acc;
#pragma unroll
    for (int d = 1; d < 64; d <<= 1) {
        double tt = __shfl_up(incl, d, 64);
        if (lane >= d) incl += tt;
    }
    if (lane == 63) wT[wave] = incl;
    if (tid < 2) survCnt[tid] = 0;
    __syncthreads();                            // P0

    double wprev = (wave & 1) ? wT[wave - 1] : 0.0;   // waves 1,3 add prior wave
    double CN = wT[2 * r] + wT[2 * r + 1];            // row grand total
    double base = wprev + (incl - tot);               // exclusive prefix
    double eps = 1e-9 * fabs(CN) + 1e-6;
    const double invN = 1.0 / (double)N;

    // ---- chord prune: C_p above chord (0,0)-(N,CN) survives ----
    {
        double cp = base;
#pragma unroll
        for (int u = 0; u < 8; ++u) {
            float fv[4] = {sv4[u].x, sv4[u].y, sv4[u].z, sv4[u].w};
#pragma unroll
            for (int c = 0; c < 4; ++c) {
                int q = q0 + 4 * u + c;
                cp += (double)fv[c] - (double)(N - q);
                int p = q + 1;
                if (p < N && cp > CN * ((double)p * invN) - eps) {
                    int slot = atomicAdd(&survCnt[r], 1);
                    if (slot < 512) {
                        survX[r][slot] = (unsigned short)p; survY[r][slot] = cp;
                    }
                }
            }
        }
    }
    __syncthreads();                            // P1

    // ---- serial per row: sort survivors, Graham upper hull, slopes ----
    if (t == 0) {                               // tid 0 (row A), tid 128 (row B)
        int kk = survCnt[r]; if (kk > 512) kk = 512;
        for (int a = 1; a < kk; ++a) {
            unsigned short vx = survX[r][a]; double vy = survY[r][a];
            int b = a - 1;
            while (b >= 0 && survX[r][b] > vx) {
                survX[r][b + 1] = survX[r][b]; survY[r][b + 1] = survY[r][b]; --b;
            }
            survX[r][b + 1] = vx; survY[r][b + 1] = vy;
        }
        int cnt2 = 0;
        int xa = 0, xb = 0; double ya = 0.0, yb = 0.0;
        for (int q = 0; q <= kk + 1; ++q) {
            int x; double cy;
            if (q == 0)       { x = 0; cy = 0.0; }
            else if (q <= kk) { x = (int)survX[r][q - 1]; cy = survY[r][q - 1]; }
            else              { x = N; cy = CN; }
            while (cnt2 >= 2) {
                double cr = (double)(xb - xa) * (cy - ya) - (yb - ya) * (double)(x - xa);
                if (cr >= 0.0) {
                    cnt2--; xb = xa; yb = ya;
                    if (cnt2 >= 2) { xa = (int)gX[r][cnt2 - 2]; ya = gY[r][cnt2 - 2]; }
                } else break;
            }
            gX[r][cnt2] = (unsigned short)x; gY[r][cnt2] = cy;
            xa = xb; ya = yb; xb = x; yb = cy;
            cnt2++;
        }
        Hsh[r] = cnt2;
        for (int q = 0; q + 1 < cnt2; ++q)      // expected cnt2==2 -> 1 divide
            gSlope[r][q] = (gY[r][q + 1] - gY[r][q]) /
                           (double)((int)gX[r][q + 1] - (int)gX[r][q]);
    }
    __syncthreads();                            // P2

    // ---- epilogue: r_i = x_i - slope(seg(pos_i)) - 2048; moments + BCE ----
    double Sa = 0, Sb = 0, Saa = 0, Sbb = 0, Sab = 0, Bce = 0;
    {
        int HA = Hsh[0], HB = Hsh[1];
#pragma unroll
        for (int u = 0; u < 4; ++u) {
            int pa[4] = {pa4[u].x, pa4[u].y, pa4[u].z, pa4[u].w};
            int pb[4] = {pb4[u].x, pb4[u].y, pb4[u].z, pb4[u].w};
            float xx[4] = {xh4[u].x, xh4[u].y, xh4[u].z, xh4[u].w};
            float yy[4] = {yt4[u].x, yt4[u].y, yt4[u].z, yt4[u].w};
#pragma unroll
            for (int j = 0; j < 4; ++j) {
                int p = pa[j];
                int a = 0, b2 = HA - 1;
                while (b2 - a > 1) {            // H==2 -> loop skipped
                    int mm = (a + b2) >> 1;
                    if ((int)gX[0][mm] <= p) a = mm; else b2 = mm;
                }
                double dualA = gSlope[0][a];
                p = pb[j];
                a = 0; b2 = HB - 1;
                while (b2 - a > 1) {
                    int mm = (a + b2) >> 1;
                    if ((int)gX[1][mm] <= p) a = mm; else b2 = mm;
                }
                double dualB = gSlope[1][a];

                double av = (double)xx[j] - dualA - 2048.0;
                double bv = (double)yy[j] - dualB - 2048.0;
                Sa += av; Sb += bv; Saa += av * av; Sbb += bv * bv; Sab += av * bv;
                float x = xx[j];
                float e = __expf(-fabsf(x));    // (0,1] -> log arg in [1,2]
                float bt = fmaxf(x, 0.0f) + __logf(1.0f + e) - x * yy[j];
                Bce += (double)bt;
            }
        }
    }
#pragma unroll
    for (int d = 32; d; d >>= 1) {
        Sa  += __shfl_xor(Sa, d, 64);  Sb  += __shfl_xor(Sb, d, 64);
        Saa += __shfl_xor(Saa, d, 64); Sbb += __shfl_xor(Sbb, d, 64);
        Sab += __shfl_xor(Sab, d, 64); Bce += __shfl_xor(Bce, d, 64);
    }
    if (lane == 0) {
        wred[wave][0] = Sa;  wred[wave][1] = Sb;  wred[wave][2] = Saa;
        wred[wave][3] = Sbb; wred[wave][4] = Sab; wred[wave][5] = Bce;
    }
    __syncthreads();                            // P3
    if (tid == 0) {
        double sa = 0, sb = 0, saa = 0, sbb = 0, sab = 0, bce = 0;
        for (int w = 0; w < 4; ++w) {
            sa += wred[w][0]; sb += wred[w][1]; saa += wred[w][2];
            sbb += wred[w][3]; sab += wred[w][4]; bce += wred[w][5];
        }
        double n = (double)N;
        double cov = sab - sa * sb / n;
        double va = saa - sa * sa / n;
        double vb = sbb - sb * sb / n;
        double spearman = cov / sqrt(va * vb);
        out[0] = (float)(1.0 - spearman + bce / n);
    }
}

extern "C" void kernel_launch(void* const* d_in, const int* in_sizes, int n_in,
                              void* d_out, int out_size, void* d_ws, size_t ws_size,
                              hipStream_t stream) {
    const float* yh = (const float*)d_in[0];
    const float* yv = (const float*)d_in[1];
    float* out = (float*)d_out;

    // workspace layout: sA, sB (desc-sorted), posA, posB
    float* sA  = (float*)d_ws;
    float* sB  = sA + N;
    int* posA  = (int*)(sB + N);
    int* posB  = posA + N;

    void* args[] = { (void*)&yh, (void*)&yv, (void*)&sA, (void*)&sB,
                     (void*)&posA, (void*)&posB, (void*)&out };
    hipLaunchCooperativeKernel((const void*)fused_kernel, dim3(256), dim3(256),
                               args, 0, stream);
}

// Round 2
// 77.049 us; speedup vs baseline: 1.6616x; 1.6616x over previous
//
#include <hip/hip_runtime.h>
#include <math.h>

#define N 4096

// ---------------------------------------------------------------------------
// K1: stable descending rank by counting — now 16 lanes per element to halve
// the per-thread dependent chain and double waves/SIMD (2 blocks/CU).
//   pos_i = #{j : x_j > x_i} + #{j<i : x_j == x_i}   (== stable argsort(-x))
//   scatter s[pos_i] = x_i  (descending sorted array)
// ---------------------------------------------------------------------------
__global__ __launch_bounds__(256) void rank_kernel(
        const float* __restrict__ yh, const float* __restrict__ yv,
        float* __restrict__ sA, float* __restrict__ sB,
        int* __restrict__ posA, int* __restrict__ posB) {
    int g = blockIdx.x * 256 + threadIdx.x;   // 0..131071
    int elem = g >> 4;                        // 0..8191
    int k = g & 15;                           // stripe
    int row = elem >> 12;
    int i = elem & (N - 1);
    const float* X = row ? yv : yh;
    float x = X[i];
    const float4* X4 = (const float4*)X;
    int cnt = 0;
    int m0 = k * 64;                          // 64 float4 = 256 elements/stripe
#pragma unroll 8
    for (int m = m0; m < m0 + 64; ++m) {
        float4 f = X4[m];
        int j = 4 * m;
        cnt += (int)(f.x > x) | ((int)(f.x == x) & (int)((j + 0) < i));
        cnt += (int)(f.y > x) | ((int)(f.y == x) & (int)((j + 1) < i));
        cnt += (int)(f.z > x) | ((int)(f.z == x) & (int)((j + 2) < i));
        cnt += (int)(f.w > x) | ((int)(f.w == x) & (int)((j + 3) < i));
    }
    cnt += __shfl_xor(cnt, 1, 16);
    cnt += __shfl_xor(cnt, 2, 16);
    cnt += __shfl_xor(cnt, 4, 16);
    cnt += __shfl_xor(cnt, 8, 16);
    if (k == 0) {
        if (row) { posB[i] = cnt; sB[cnt] = x; }
        else     { posA[i] = cnt; sA[cnt] = x; }
    }
}

// ---------------------------------------------------------------------------
// K2: both rows concurrently (waves 0-7 row A, 8-15 row B). Identical math to
// the round-0 kernel; only change: S loads issued FIRST (scan consumes them
// immediately — critical path), epilogue loads after (not needed until B3).
// ---------------------------------------------------------------------------
__global__ __launch_bounds__(1024) void finalize_kernel(
        const float* __restrict__ yh, const float* __restrict__ yv,
        const float* __restrict__ sA, const float* __restrict__ sB,
        const int* __restrict__ posA, const int* __restrict__ posB,
        float* __restrict__ out) {
    __shared__ double wtot[2][8];
    __shared__ double CNsh[2];
    __shared__ unsigned short survX[2][512];
    __shared__ double survY[2][512];
    __shared__ unsigned short gX[2][516];
    __shared__ double gY[2][516];
    __shared__ double gSlope[2][516];
    __shared__ int survCnt[2];
    __shared__ int Hsh[2];
    __shared__ double wred[16][6];             // total ~30 KB

    const int tid  = threadIdx.x;
    const int lane = tid & 63;
    const int wave = tid >> 6;
    const int r    = tid >> 9;                 // 0: row A, 1: row B
    const int ht   = tid & 511;
    const int hw   = wave & 7;
    const int q0   = ht * 8;

    // critical-path loads first: sorted values for the scan
    const float* S = r ? sB : sA;
    float4 sa4 = ((const float4*)S)[2 * ht];
    float4 sb4 = ((const float4*)S)[2 * ht + 1];

    // epilogue loads issued next to hide global latency under scan/hull
    int4 pa4 = ((const int4*)posA)[tid];
    int4 pb4 = ((const int4*)posB)[tid];
    float4 xh = ((const float4*)yh)[tid];
    float4 yt = ((const float4*)yv)[tid];

    float sv[8] = {sa4.x, sa4.y, sa4.z, sa4.w, sb4.x, sb4.y, sb4.z, sb4.w};

    // ---- per-thread running prefix of z over 8 elements (registers) ----
    double m[8];
    double acc = 0.0;
#pragma unroll
    for (int j = 0; j < 8; ++j) {
        acc += (double)sv[j] - (double)(N - (q0 + j));
        m[j] = acc;
    }
    double tot = m[7], incl = tot;
#pragma unroll
    for (int d = 1; d < 64; d <<= 1) {
        double t = __shfl_up(incl, d, 64);
        if (lane >= d) incl += t;
    }
    if (lane == 63) wtot[r][hw] = incl;
    if (tid < 2) survCnt[tid] = 0;
    __syncthreads();                           // B0

    if (tid < 16) {
        int rr = tid >> 3, idx = tid & 7;
        double v = wtot[rr][idx], inc = v;
#pragma unroll
        for (int d = 1; d < 8; d <<= 1) {
            double t = __shfl_up(inc, d, 8);
            if (idx >= d) inc += t;
        }
        wtot[rr][idx] = inc - v;               // exclusive
        if (idx == 7) CNsh[rr] = inc;          // grand total = C_N
    }
    __syncthreads();                           // B1

    double base = wtot[r][hw] + (incl - tot);
    double CN = CNsh[r];
    double eps = 1e-9 * fabs(CN) + 1e-6;
    const double invN = 1.0 / (double)N;

    // ---- chord prune: C_p = base + m[j], all registers ----
#pragma unroll
    for (int j = 0; j < 8; ++j) {
        int p = q0 + 1 + j;
        if (p < N) {
            double cp = base + m[j];
            if (cp > CN * ((double)p * invN) - eps) {
                int slot = atomicAdd(&survCnt[r], 1);
                if (slot < 512) { survX[r][slot] = (unsigned short)p; survY[r][slot] = cp; }
            }
        }
    }
    __syncthreads();                           // B2

    // ---- serial per row: sort survivors, Graham upper hull, slopes ----
    if (ht == 0) {                             // tid 0 (row A) and tid 512 (row B)
        int k = survCnt[r]; if (k > 512) k = 512;
        for (int a = 1; a < k; ++a) {
            unsigned short vx = survX[r][a]; double vy = survY[r][a];
            int b = a - 1;
            while (b >= 0 && survX[r][b] > vx) {
                survX[r][b + 1] = survX[r][b]; survY[r][b + 1] = survY[r][b]; --b;
            }
            survX[r][b + 1] = vx; survY[r][b + 1] = vy;
        }
        int cnt = 0;
        int xa = 0, xb = 0; double ya = 0.0, yb = 0.0;
        for (int q = 0; q <= k + 1; ++q) {
            int x; double cy;
            if (q == 0)      { x = 0; cy = 0.0; }
            else if (q <= k) { x = (int)survX[r][q - 1]; cy = survY[r][q - 1]; }
            else             { x = N; cy = CN; }
            while (cnt >= 2) {
                double cr = (double)(xb - xa) * (cy - ya) - (yb - ya) * (double)(x - xa);
                if (cr >= 0.0) {
                    cnt--; xb = xa; yb = ya;
                    if (cnt >= 2) { xa = (int)gX[r][cnt - 2]; ya = gY[r][cnt - 2]; }
                } else break;
            }
            gX[r][cnt] = (unsigned short)x; gY[r][cnt] = cy;
            xa = xb; ya = yb; xb = x; yb = cy;
            cnt++;
        }
        Hsh[r] = cnt;
        for (int q = 0; q + 1 < cnt; ++q)      // expected cnt==2 -> 1 divide
            gSlope[r][q] = (gY[r][q + 1] - gY[r][q]) /
                           (double)((int)gX[r][q + 1] - (int)gX[r][q]);
    }
    __syncthreads();                           // B3

    // ---- epilogue: r_i = x_i - slope(seg(pos_i)) - 2048; moments + BCE ----
    double Sa = 0, Sb = 0, Saa = 0, Sbb = 0, Sab = 0, Bce = 0;
    {
        int HA = Hsh[0], HB = Hsh[1];
        int pa[4] = {pa4.x, pa4.y, pa4.z, pa4.w};
        int pb[4] = {pb4.x, pb4.y, pb4.z, pb4.w};
        float xx[4] = {xh.x, xh.y, xh.z, xh.w};
        float yy[4] = {yt.x, yt.y, yt.z, yt.w};
#pragma unroll
        for (int j = 0; j < 4; ++j) {
            int p = pa[j];
            int a = 0, b2 = HA - 1;
            while (b2 - a > 1) {               // H==2 -> loop skipped
                int mm = (a + b2) >> 1;
                if ((int)gX[0][mm] <= p) a = mm; else b2 = mm;
            }
            double dualA = gSlope[0][a];
            p = pb[j];
            a = 0; b2 = HB - 1;
            while (b2 - a > 1) {
                int mm = (a + b2) >> 1;
                if ((int)gX[1][mm] <= p) a = mm; else b2 = mm;
            }
            double dualB = gSlope[1][a];

            double av = (double)xx[j] - dualA - 2048.0;
            double bv = (double)yy[j] - dualB - 2048.0;
            Sa += av; Sb += bv; Saa += av * av; Sbb += bv * bv; Sab += av * bv;
            float x = xx[j];
            float e = __expf(-fabsf(x));           // (0,1] -> log arg in [1,2]
            float bt = fmaxf(x, 0.0f) + __logf(1.0f + e) - x * yy[j];
            Bce += (double)bt;
        }
    }
#pragma unroll
    for (int d = 32; d; d >>= 1) {
        Sa  += __shfl_xor(Sa, d, 64);  Sb  += __shfl_xor(Sb, d, 64);
        Saa += __shfl_xor(Saa, d, 64); Sbb += __shfl_xor(Sbb, d, 64);
        Sab += __shfl_xor(Sab, d, 64); Bce += __shfl_xor(Bce, d, 64);
    }
    if (lane == 0) {
        wred[wave][0] = Sa;  wred[wave][1] = Sb;  wred[wave][2] = Saa;
        wred[wave][3] = Sbb; wred[wave][4] = Sab; wred[wave][5] = Bce;
    }
    __syncthreads();                           // B4
    if (tid == 0) {
        double sa = 0, sb = 0, saa = 0, sbb = 0, sab = 0, bce = 0;
        for (int w = 0; w < 16; ++w) {
            sa += wred[w][0]; sb += wred[w][1]; saa += wred[w][2];
            sbb += wred[w][3]; sab += wred[w][4]; bce += wred[w][5];
        }
        double n = (double)N;
        double cov = sab - sa * sb / n;
        double va = saa - sa * sa / n;
        double vb = sbb - sb * sb / n;
        double spearman = cov / sqrt(va * vb);
        out[0] = (float)(1.0 - spearman + bce / n);
    }
}

extern "C" void kernel_launch(void* const* d_in, const int* in_sizes, int n_in,
                              void* d_out, int out_size, void* d_ws, size_t ws_size,
                              hipStream_t stream) {
    const float* yh = (const float*)d_in[0];
    const float* yv = (const float*)d_in[1];
    float* out = (float*)d_out;

    // workspace layout: sA, sB (desc-sorted), posA, posB
    float* sA  = (float*)d_ws;
    float* sB  = sA + N;
    int* posA  = (int*)(sB + N);
    int* posB  = posA + N;

    hipLaunchKernelGGL(rank_kernel, dim3(512), dim3(256), 0, stream,
                       yh, yv, sA, sB, posA, posB);
    hipLaunchKernelGGL(finalize_kernel, dim3(1), dim3(1024), 0, stream,
                       yh, yv, sA, sB, posA, posB, out);
}